// Round 1
// baseline (341.852 us; speedup 1.0000x reference)
//
#include <hip/hip_runtime.h>

#define B_DIM 8192
#define CELL  1024
#define KA    3328   // A_full row: 1024 x | 1024 htm | 256 spk | 1024 ztm
#define KT4   2304   // gates weight K
#define NSUM  5120   // sums row: 4096 gates | 1024 hybrid

typedef unsigned short u16;
typedef __attribute__((ext_vector_type(8))) short bf16x8;
typedef __attribute__((ext_vector_type(4))) float f32x4;
typedef __attribute__((ext_vector_type(4))) float fx4;
typedef __attribute__((ext_vector_type(4))) unsigned short u16x4;

__device__ inline u16 f2bf(float f) {
  unsigned u = __float_as_uint(f);
  return (u16)((u + 0x7FFFu + ((u >> 16) & 1u)) >> 16);
}
__device__ inline float bf2f(u16 h) { return __uint_as_float(((unsigned)h) << 16); }
__device__ inline float sigmoidf(float v) { return 1.0f / (1.0f + __expf(-v)); }

// ---------- prep: fp32 -> bf16 concat into A_full ----------
__global__ void cvt_cat(const float* __restrict__ src, u16* __restrict__ dst,
                        int shift, int colOff, int n4) {
  int i = blockIdx.x * 256 + threadIdx.x;
  if (i >= n4) return;
  int e = i << 2;
  int row = e >> shift;
  int col = e & ((1 << shift) - 1);
  float4 v = *reinterpret_cast<const float4*>(src + e);
  u16x4 o;
  o[0] = f2bf(v.x); o[1] = f2bf(v.y); o[2] = f2bf(v.z); o[3] = f2bf(v.w);
  *reinterpret_cast<u16x4*>(dst + (size_t)row * KA + colOff + col) = o;
}

// ---------- prep: transpose weights [K][N] fp32 -> [N][KT] bf16 ----------
__global__ void wtrans(const float* __restrict__ src, int N,
                       u16* __restrict__ dst, int KT, int koff) {
  __shared__ float tile[32][33];
  int n0 = blockIdx.x * 32, k0 = blockIdx.y * 32;
  int tx = threadIdx.x, ty = threadIdx.y;  // 32x8
#pragma unroll
  for (int j = 0; j < 4; ++j)
    tile[ty + j * 8][tx] = src[(size_t)(k0 + ty + j * 8) * N + n0 + tx];
  __syncthreads();
#pragma unroll
  for (int j = 0; j < 4; ++j)
    dst[(size_t)(n0 + ty + j * 8) * KT + koff + k0 + tx] = f2bf(tile[tx][ty + j * 8]);
}

// ---------- GEMM (m97 structure: 128x128 tile, BK=32, global_load_lds) ----------
__device__ inline void gload_lds16(const void* g, void* l) {
  __builtin_amdgcn_global_load_lds((const __attribute__((address_space(1))) void*)g,
                                   (__attribute__((address_space(3))) void*)l,
                                   16, 0, 0);
}

// stage a [128][32] bf16 tile (8KB): 2 x 1KB-per-wave chunks, lane writes 16B
__device__ inline void stage_tile(const u16* __restrict__ src, int ld,
                                  u16* lds, int wave, int lane) {
#pragma unroll
  for (int c = 0; c < 2; ++c) {
    int row = wave * 16 + c * 64 + (lane >> 2);
    int col = (lane & 3) * 8;
    const u16* g = src + (size_t)row * ld + col;
    char* l = (char*)lds + wave * 1024 + c * 4096;  // wave-uniform base; HW adds lane*16
    gload_lds16((const void*)g, (void*)l);
  }
}

__global__ __launch_bounds__(256) void gemm_all(
    const u16* __restrict__ Afull, const u16* __restrict__ WT4a,
    const u16* __restrict__ WTVa, u16* __restrict__ sums) {
  __shared__ u16 As[2][128 * 32];
  __shared__ u16 Bs[2][128 * 32];
  const int tid = threadIdx.x;
  const int wave = tid >> 6, lane = tid & 63;
  const int wr = wave >> 1, wc = wave & 1;
  const int bx = blockIdx.x, by = blockIdx.y;

  const u16* Bsrc; int KT, nbase, aoff, nk, ncol0;
  if (bx < 32) { Bsrc = WT4a; KT = KT4;  nbase = bx * 128;        aoff = 0;    nk = 72; ncol0 = bx * 128; }
  else         { Bsrc = WTVa; KT = 1024; nbase = (bx - 32) * 128; aoff = 2304; nk = 32; ncol0 = 4096 + (bx - 32) * 128; }
  const int m0 = by * 128;
  const u16* Ab = Afull + (size_t)m0 * KA + aoff;
  const u16* Bb = Bsrc + (size_t)nbase * KT;

  f32x4 acc[4][4];
#pragma unroll
  for (int m = 0; m < 4; ++m)
#pragma unroll
    for (int n = 0; n < 4; ++n) acc[m][n] = (f32x4){0.f, 0.f, 0.f, 0.f};

  stage_tile(Ab, KA, As[0], wave, lane);
  stage_tile(Bb, KT, Bs[0], wave, lane);

  for (int kt = 0; kt < nk; ++kt) {
    const int buf = kt & 1;
    __syncthreads();  // compiler drains vmcnt(0) here -> staged tile [buf] is ready
    if (kt + 1 < nk) {
      stage_tile(Ab + (kt + 1) * 32, KA, As[buf ^ 1], wave, lane);
      stage_tile(Bb + (kt + 1) * 32, KT, Bs[buf ^ 1], wave, lane);
    }
    const int kcol = (lane >> 4) * 8;
    const int lrow = lane & 15;
    bf16x8 a[4], b[4];
#pragma unroll
    for (int m = 0; m < 4; ++m)
      a[m] = *reinterpret_cast<const bf16x8*>(&As[buf][(wr * 64 + m * 16 + lrow) * 32 + kcol]);
#pragma unroll
    for (int n = 0; n < 4; ++n)
      b[n] = *reinterpret_cast<const bf16x8*>(&Bs[buf][(wc * 64 + n * 16 + lrow) * 32 + kcol]);
#pragma unroll
    for (int m = 0; m < 4; ++m)
#pragma unroll
      for (int n = 0; n < 4; ++n)
        acc[m][n] = __builtin_amdgcn_mfma_f32_16x16x32_bf16(a[m], b[n], acc[m][n], 0, 0, 0);
  }

  // C-write: col = lane&15, row = (lane>>4)*4 + j  (verified m89 layout)
#pragma unroll
  for (int m = 0; m < 4; ++m) {
#pragma unroll
    for (int n = 0; n < 4; ++n) {
      int col = ncol0 + wc * 64 + n * 16 + (lane & 15);
      int rbase = m0 + wr * 64 + m * 16 + (lane >> 4) * 4;
#pragma unroll
      for (int j = 0; j < 4; ++j)
        sums[(size_t)(rbase + j) * NSUM + col] = f2bf(acc[m][n][j]);
    }
  }
}

// ---------- fused LSTM epilogue (fp32) ----------
__global__ void epilogue(const u16* __restrict__ sums, const float* __restrict__ ctm,
                         const float* __restrict__ Wb, const float* __restrict__ Ub,
                         const float* __restrict__ Sb, const float* __restrict__ Vb,
                         float* __restrict__ outC, float* __restrict__ outH) {
  int t = blockIdx.x * 256 + threadIdx.x;
  int row = t >> 8;
  int c4 = (t & 255) << 2;
  const u16* s = sums + (size_t)row * NSUM;
  u16x4 sf = *reinterpret_cast<const u16x4*>(s + c4);
  u16x4 si = *reinterpret_cast<const u16x4*>(s + 1024 + c4);
  u16x4 so = *reinterpret_cast<const u16x4*>(s + 2048 + c4);
  u16x4 sc = *reinterpret_cast<const u16x4*>(s + 3072 + c4);
  u16x4 sh = *reinterpret_cast<const u16x4*>(s + 4096 + c4);
  fx4 ct = *reinterpret_cast<const fx4*>(ctm + (size_t)row * CELL + c4);
  fx4 bF = *reinterpret_cast<const fx4*>(Wb + c4) +
           *reinterpret_cast<const fx4*>(Ub + c4) +
           *reinterpret_cast<const fx4*>(Sb + c4);
  fx4 bI = *reinterpret_cast<const fx4*>(Wb + 1024 + c4) +
           *reinterpret_cast<const fx4*>(Ub + 1024 + c4) +
           *reinterpret_cast<const fx4*>(Sb + 1024 + c4);
  fx4 bO = *reinterpret_cast<const fx4*>(Wb + 2048 + c4) +
           *reinterpret_cast<const fx4*>(Ub + 2048 + c4) +
           *reinterpret_cast<const fx4*>(Sb + 2048 + c4);
  fx4 bC = *reinterpret_cast<const fx4*>(Wb + 3072 + c4) +
           *reinterpret_cast<const fx4*>(Ub + 3072 + c4) +
           *reinterpret_cast<const fx4*>(Sb + 3072 + c4);
  fx4 bH = *reinterpret_cast<const fx4*>(Vb + c4);

  fx4 vc, vh;
#pragma unroll
  for (int j = 0; j < 4; ++j) {
    float f_ = sigmoidf(bf2f(sf[j]) + bF[j]);
    float i_ = sigmoidf(bf2f(si[j]) + bI[j]);
    float o_ = sigmoidf(bf2f(so[j]) + bO[j]);
    float g_ = tanhf(bf2f(sc[j]) + bC[j]);
    float fh = sigmoidf(bf2f(sh[j]) + bH[j]);
    float cc = (f_ + fh) * ct[j] + i_ * g_;
    vc[j] = cc;
    vh[j] = tanhf(cc) * o_;
  }
  *reinterpret_cast<fx4*>(outC + (size_t)row * CELL + c4) = vc;
  *reinterpret_cast<fx4*>(outH + (size_t)row * CELL + c4) = vh;
}

extern "C" void kernel_launch(void* const* d_in, const int* in_sizes, int n_in,
                              void* d_out, int out_size, void* d_ws, size_t ws_size,
                              hipStream_t stream) {
  const float* x   = (const float*)d_in[0];
  const float* ctm = (const float*)d_in[1];
  const float* htm = (const float*)d_in[2];
  const float* ztm = (const float*)d_in[3];
  const float* spk = (const float*)d_in[4];
  const float* Ww  = (const float*)d_in[5];
  const float* Wb  = (const float*)d_in[6];
  const float* Uw  = (const float*)d_in[7];
  const float* Ub  = (const float*)d_in[8];
  const float* Vw  = (const float*)d_in[9];
  const float* Vb  = (const float*)d_in[10];
  const float* Sw  = (const float*)d_in[11];
  const float* Sb  = (const float*)d_in[12];

  // workspace layout (bf16 elements): A_full | WT4 | WTV | sums  (~159 MB)
  u16* Afull = (u16*)d_ws;
  u16* WT4a  = Afull + (size_t)B_DIM * KA;
  u16* WTVa  = WT4a + (size_t)4096 * KT4;
  u16* sums  = WTVa + (size_t)1024 * 1024;
  float* outC = (float*)d_out;
  float* outH = outC + (size_t)B_DIM * CELL;

  cvt_cat<<<8192, 256, 0, stream>>>(x,   Afull, 10, 0,    2097152);
  cvt_cat<<<8192, 256, 0, stream>>>(htm, Afull, 10, 1024, 2097152);
  cvt_cat<<<2048, 256, 0, stream>>>(spk, Afull, 8,  2048, 524288);
  cvt_cat<<<8192, 256, 0, stream>>>(ztm, Afull, 10, 2304, 2097152);

  wtrans<<<dim3(128, 32), dim3(32, 8), 0, stream>>>(Ww, 4096, WT4a, KT4, 0);
  wtrans<<<dim3(128, 32), dim3(32, 8), 0, stream>>>(Uw, 4096, WT4a, KT4, 1024);
  wtrans<<<dim3(128, 8),  dim3(32, 8), 0, stream>>>(Sw, 4096, WT4a, KT4, 2048);
  wtrans<<<dim3(32, 32),  dim3(32, 8), 0, stream>>>(Vw, 1024, WTVa, 1024, 0);

  gemm_all<<<dim3(40, 64), 256, 0, stream>>>(Afull, WT4a, WTVa, sums);

  epilogue<<<8192, 256, 0, stream>>>(sums, ctm, Wb, Ub, Sb, Vb, outC, outH);
}

// Round 2
// 295.535 us; speedup vs baseline: 1.1567x; 1.1567x over previous
//
#include <hip/hip_runtime.h>

#define B_DIM 8192
#define CELL  1024
#define KA    3328   // A_full row: 1024 x | 1024 htm | 256 spk | 1024 ztm
#define NSUM  5120   // sums row: 4096 gates | 1024 hybrid
#define BM    256
#define BN    256
#define BK    64

typedef unsigned short u16;
typedef __attribute__((ext_vector_type(8))) short bf16x8;
typedef __attribute__((ext_vector_type(4))) float f32x4;
typedef __attribute__((ext_vector_type(4))) float fx4;
typedef __attribute__((ext_vector_type(4))) unsigned short u16x4;

__device__ inline u16 f2bf(float f) {
  unsigned u = __float_as_uint(f);
  return (u16)((u + 0x7FFFu + ((u >> 16) & 1u)) >> 16);
}
__device__ inline float bf2f(u16 h) { return __uint_as_float(((unsigned)h) << 16); }
__device__ inline float sigmoidf(float v) { return 1.0f / (1.0f + __expf(-v)); }

// ---------- prep: fp32 -> bf16 concat into A_full ----------
__global__ void cvt_cat(const float* __restrict__ src, u16* __restrict__ dst,
                        int shift, int colOff, int n4) {
  int i = blockIdx.x * 256 + threadIdx.x;
  if (i >= n4) return;
  int e = i << 2;
  int row = e >> shift;
  int col = e & ((1 << shift) - 1);
  float4 v = *reinterpret_cast<const float4*>(src + e);
  u16x4 o;
  o[0] = f2bf(v.x); o[1] = f2bf(v.y); o[2] = f2bf(v.z); o[3] = f2bf(v.w);
  *reinterpret_cast<u16x4*>(dst + (size_t)row * KA + colOff + col) = o;
}

// ---------- prep: transpose weights [K][N] fp32 -> [N][KT] bf16 ----------
__global__ void wtrans(const float* __restrict__ src, int N,
                       u16* __restrict__ dst, int KT, int koff) {
  __shared__ float tile[32][33];
  int n0 = blockIdx.x * 32, k0 = blockIdx.y * 32;
  int tx = threadIdx.x, ty = threadIdx.y;  // 32x8
#pragma unroll
  for (int j = 0; j < 4; ++j)
    tile[ty + j * 8][tx] = src[(size_t)(k0 + ty + j * 8) * N + n0 + tx];
  __syncthreads();
#pragma unroll
  for (int j = 0; j < 4; ++j)
    dst[(size_t)(n0 + ty + j * 8) * KT + koff + k0 + tx] = f2bf(tile[tx][ty + j * 8]);
}

// ---------- 256x256 8-phase GEMM (T2 swizzle + T3/T4 counted vmcnt + T5) ----------
__device__ __forceinline__ void gload_lds16(const void* g, void* l) {
  __builtin_amdgcn_global_load_lds((const __attribute__((address_space(1))) void*)g,
                                   (__attribute__((address_space(3))) void*)l,
                                   16, 0, 0);
}

// stage one half (128 rows x 64 k) of a [256][64] bf16 tile: 2 x global_load_lds.
// LDS dest is LINEAR (wave-uniform base + lane*16); the global SOURCE slot is
// pre-XOR-swizzled so that ds_read-with-XOR sees the right data (rule 21).
__device__ __forceinline__ void stage_half(const u16* __restrict__ g0, int ldk,
                                           u16* ldsTile, int half, int kt,
                                           int wave, int lane) {
#pragma unroll
  for (int k2 = 0; k2 < 2; ++k2) {
    const int r0 = half * 128 + k2 * 64 + wave * 8;   // wave-uniform row base
    const int r = r0 + (lane >> 3);                   // this lane's row (r&7 == lane>>3)
    const int slot = (lane & 7) ^ (lane >> 3);        // pre-swizzled 16B slot
    const u16* g = g0 + (size_t)r * ldk + kt * 64 + slot * 8;
    gload_lds16((const void*)g, (void*)(ldsTile + r0 * 64));
  }
}

#define LD_A(ASP, QP)                                                              \
  aq[0][0] = *reinterpret_cast<const bf16x8*>((ASP) + aBase0 + (2 * (QP)) * 1024);     \
  aq[0][1] = *reinterpret_cast<const bf16x8*>((ASP) + aBase1 + (2 * (QP)) * 1024);     \
  aq[1][0] = *reinterpret_cast<const bf16x8*>((ASP) + aBase0 + (2 * (QP) + 1) * 1024); \
  aq[1][1] = *reinterpret_cast<const bf16x8*>((ASP) + aBase1 + (2 * (QP) + 1) * 1024);

#define LD_B(BSP)                                                                  \
  _Pragma("unroll")                                                                \
  for (int n = 0; n < 4; ++n) {                                                    \
    br[n][0] = *reinterpret_cast<const bf16x8*>((BSP) + bBase0 + n * 1024);        \
    br[n][1] = *reinterpret_cast<const bf16x8*>((BSP) + bBase1 + n * 1024);        \
  }

#define MFMA_PH(QP)                                                                \
  __builtin_amdgcn_s_setprio(1);                                                   \
  _Pragma("unroll")                                                                \
  for (int q = 0; q < 2; ++q) {                                                    \
    _Pragma("unroll")                                                              \
    for (int n = 0; n < 4; ++n) {                                                  \
      acc[2 * (QP) + q][n] = __builtin_amdgcn_mfma_f32_16x16x32_bf16(              \
          aq[q][0], br[n][0], acc[2 * (QP) + q][n], 0, 0, 0);                      \
      acc[2 * (QP) + q][n] = __builtin_amdgcn_mfma_f32_16x16x32_bf16(              \
          aq[q][1], br[n][1], acc[2 * (QP) + q][n], 0, 0, 0);                      \
    }                                                                              \
  }                                                                                \
  __builtin_amdgcn_s_setprio(0);

#define ENTRY_BAR                                                                  \
  __builtin_amdgcn_sched_barrier(0);                                               \
  __builtin_amdgcn_s_barrier();                                                    \
  asm volatile("s_waitcnt lgkmcnt(0)" ::: "memory");                               \
  __builtin_amdgcn_sched_barrier(0);

#define EXIT_BAR __builtin_amdgcn_s_barrier();

__global__ __launch_bounds__(512, 2) void gemm8(
    const u16* __restrict__ Afull, const u16* __restrict__ WT4a,
    const u16* __restrict__ WTVa, u16* __restrict__ sums) {
  __shared__ u16 As[2][BM * BK];
  __shared__ u16 Bs[2][BN * BK];
  const int tid = threadIdx.x;
  const int wave = tid >> 6, lane = tid & 63;
  const int wm = wave >> 2, wn = wave & 3;       // 2 x 4 wave grid
  const int lrow = lane & 15, khi = lane >> 4;

  const int bx = blockIdx.x, by = blockIdx.y;
  const u16* Bsrc; int KT, nk, ncol0, aoff, nbase;
  if (bx < 16) { Bsrc = WT4a; KT = 2304; nk = 36; nbase = bx * 256; ncol0 = bx * 256; aoff = 0; }
  else         { Bsrc = WTVa; KT = 1024; nk = 16; nbase = (bx - 16) * 256; ncol0 = 4096 + (bx - 16) * 256; aoff = 2304; }
  const int m0 = by * 256;
  const u16* Ag = Afull + (size_t)m0 * KA + aoff;
  const u16* Bg = Bsrc + (size_t)nbase * KT;

  // read-side swizzled 16B-slot offsets (element units); row&7 == lane&7 for reads
  const int sw = lane & 7;
  const int swz0 = ((0 + khi) ^ sw) * 8;   // ks=0 slot
  const int swz1 = ((4 + khi) ^ sw) * 8;   // ks=1 slot
  const int aBase0 = (wm * 128 + lrow) * 64 + swz0;
  const int aBase1 = (wm * 128 + lrow) * 64 + swz1;
  const int bBase0 = (wn * 64 + lrow) * 64 + swz0;
  const int bBase1 = (wn * 64 + lrow) * 64 + swz1;

  f32x4 acc[8][4];
#pragma unroll
  for (int m2 = 0; m2 < 8; ++m2)
#pragma unroll
    for (int n2 = 0; n2 < 4; ++n2) acc[m2][n2] = (f32x4){0.f, 0.f, 0.f, 0.f};
  bf16x8 aq[2][2], br[4][2];
  u16* As0 = As[0]; u16* As1 = As[1]; u16* Bs0 = Bs[0]; u16* Bs1 = Bs[1];

  // prologue: t0 fully + t1.B; retire t0, leave t1.B (4 loads) in flight
  stage_half(Ag, KA, As0, 0, 0, wave, lane);
  stage_half(Ag, KA, As0, 1, 0, wave, lane);
  stage_half(Bg, KT, Bs0, 0, 0, wave, lane);
  stage_half(Bg, KT, Bs0, 1, 0, wave, lane);
  stage_half(Bg, KT, Bs1, 0, 1, wave, lane);
  stage_half(Bg, KT, Bs1, 1, 1, wave, lane);
  asm volatile("s_waitcnt vmcnt(4)" ::: "memory");
  __builtin_amdgcn_s_barrier();

  const int niter = nk >> 1;
  for (int it = 0; it < niter; ++it) {
    const int t = it * 2;
    const bool nl = (t + 2 < nk);
    // ---- phases 0-3: compute tile t from buf0 ----
    LD_B(Bs0)
    LD_A(As0, 0)
    stage_half(Ag, KA, As1, 0, t + 1, wave, lane);
    ENTRY_BAR MFMA_PH(0) EXIT_BAR

    LD_A(As0, 1)
    stage_half(Ag, KA, As1, 1, t + 1, wave, lane);
    ENTRY_BAR MFMA_PH(1) EXIT_BAR

    LD_A(As0, 2)
    if (nl) stage_half(Bg, KT, Bs0, 0, t + 2, wave, lane);
    ENTRY_BAR MFMA_PH(2) EXIT_BAR

    LD_A(As0, 3)
    if (nl) stage_half(Bg, KT, Bs0, 1, t + 2, wave, lane);
    ENTRY_BAR MFMA_PH(3)
    if (nl) { asm volatile("s_waitcnt vmcnt(4)" ::: "memory"); }
    else    { asm volatile("s_waitcnt vmcnt(0)" ::: "memory"); }
    EXIT_BAR

    // ---- phases 4-7: compute tile t+1 from buf1 ----
    LD_B(Bs1)
    LD_A(As1, 0)
    if (nl) stage_half(Ag, KA, As0, 0, t + 2, wave, lane);
    ENTRY_BAR MFMA_PH(0) EXIT_BAR

    LD_A(As1, 1)
    if (nl) stage_half(Ag, KA, As0, 1, t + 2, wave, lane);
    ENTRY_BAR MFMA_PH(1) EXIT_BAR

    LD_A(As1, 2)
    if (nl) stage_half(Bg, KT, Bs1, 0, t + 3, wave, lane);
    ENTRY_BAR MFMA_PH(2) EXIT_BAR

    LD_A(As1, 3)
    if (nl) stage_half(Bg, KT, Bs1, 1, t + 3, wave, lane);
    ENTRY_BAR MFMA_PH(3)
    if (nl) { asm volatile("s_waitcnt vmcnt(4)" ::: "memory"); }
    else    { asm volatile("s_waitcnt vmcnt(0)" ::: "memory"); }
    EXIT_BAR
  }

  // C-write: col = lane&15, row = (lane>>4)*4 + j (verified m89 layout)
#pragma unroll
  for (int mf = 0; mf < 8; ++mf) {
    const int rbase = m0 + wm * 128 + mf * 16 + khi * 4;
#pragma unroll
    for (int nf = 0; nf < 4; ++nf) {
      const int col = ncol0 + wn * 64 + nf * 16 + lrow;
#pragma unroll
      for (int j = 0; j < 4; ++j)
        sums[(size_t)(rbase + j) * NSUM + col] = f2bf(acc[mf][nf][j]);
    }
  }
}

// ---------- fused LSTM epilogue (fp32) ----------
__global__ void epilogue(const u16* __restrict__ sums, const float* __restrict__ ctm,
                         const float* __restrict__ Wb, const float* __restrict__ Ub,
                         const float* __restrict__ Sb, const float* __restrict__ Vb,
                         float* __restrict__ outC, float* __restrict__ outH) {
  int t = blockIdx.x * 256 + threadIdx.x;
  int row = t >> 8;
  int c4 = (t & 255) << 2;
  const u16* s = sums + (size_t)row * NSUM;
  u16x4 sf = *reinterpret_cast<const u16x4*>(s + c4);
  u16x4 si = *reinterpret_cast<const u16x4*>(s + 1024 + c4);
  u16x4 so = *reinterpret_cast<const u16x4*>(s + 2048 + c4);
  u16x4 sc = *reinterpret_cast<const u16x4*>(s + 3072 + c4);
  u16x4 sh = *reinterpret_cast<const u16x4*>(s + 4096 + c4);
  fx4 ct = *reinterpret_cast<const fx4*>(ctm + (size_t)row * CELL + c4);
  fx4 bF = *reinterpret_cast<const fx4*>(Wb + c4) +
           *reinterpret_cast<const fx4*>(Ub + c4) +
           *reinterpret_cast<const fx4*>(Sb + c4);
  fx4 bI = *reinterpret_cast<const fx4*>(Wb + 1024 + c4) +
           *reinterpret_cast<const fx4*>(Ub + 1024 + c4) +
           *reinterpret_cast<const fx4*>(Sb + 1024 + c4);
  fx4 bO = *reinterpret_cast<const fx4*>(Wb + 2048 + c4) +
           *reinterpret_cast<const fx4*>(Ub + 2048 + c4) +
           *reinterpret_cast<const fx4*>(Sb + 2048 + c4);
  fx4 bC = *reinterpret_cast<const fx4*>(Wb + 3072 + c4) +
           *reinterpret_cast<const fx4*>(Ub + 3072 + c4) +
           *reinterpret_cast<const fx4*>(Sb + 3072 + c4);
  fx4 bH = *reinterpret_cast<const fx4*>(Vb + c4);

  fx4 vc, vh;
#pragma unroll
  for (int j = 0; j < 4; ++j) {
    float f_ = sigmoidf(bf2f(sf[j]) + bF[j]);
    float i_ = sigmoidf(bf2f(si[j]) + bI[j]);
    float o_ = sigmoidf(bf2f(so[j]) + bO[j]);
    float g_ = tanhf(bf2f(sc[j]) + bC[j]);
    float fh = sigmoidf(bf2f(sh[j]) + bH[j]);
    float cc = (f_ + fh) * ct[j] + i_ * g_;
    vc[j] = cc;
    vh[j] = tanhf(cc) * o_;
  }
  *reinterpret_cast<fx4*>(outC + (size_t)row * CELL + c4) = vc;
  *reinterpret_cast<fx4*>(outH + (size_t)row * CELL + c4) = vh;
}

extern "C" void kernel_launch(void* const* d_in, const int* in_sizes, int n_in,
                              void* d_out, int out_size, void* d_ws, size_t ws_size,
                              hipStream_t stream) {
  const float* x   = (const float*)d_in[0];
  const float* ctm = (const float*)d_in[1];
  const float* htm = (const float*)d_in[2];
  const float* ztm = (const float*)d_in[3];
  const float* spk = (const float*)d_in[4];
  const float* Ww  = (const float*)d_in[5];
  const float* Wb  = (const float*)d_in[6];
  const float* Uw  = (const float*)d_in[7];
  const float* Ub  = (const float*)d_in[8];
  const float* Vw  = (const float*)d_in[9];
  const float* Vb  = (const float*)d_in[10];
  const float* Sw  = (const float*)d_in[11];
  const float* Sb  = (const float*)d_in[12];

  // workspace layout (bf16 elements): A_full | WT4 | WTV | sums  (~159 MB)
  u16* Afull = (u16*)d_ws;
  u16* WT4a  = Afull + (size_t)B_DIM * KA;
  u16* WTVa  = WT4a + (size_t)4096 * 2304;
  u16* sums  = WTVa + (size_t)1024 * 1024;
  float* outC = (float*)d_out;
  float* outH = outC + (size_t)B_DIM * CELL;

  cvt_cat<<<8192, 256, 0, stream>>>(x,   Afull, 10, 0,    2097152);
  cvt_cat<<<8192, 256, 0, stream>>>(htm, Afull, 10, 1024, 2097152);
  cvt_cat<<<2048, 256, 0, stream>>>(spk, Afull, 8,  2048, 524288);
  cvt_cat<<<8192, 256, 0, stream>>>(ztm, Afull, 10, 2304, 2097152);

  wtrans<<<dim3(128, 32), dim3(32, 8), 0, stream>>>(Ww, 4096, WT4a, 2304, 0);
  wtrans<<<dim3(128, 32), dim3(32, 8), 0, stream>>>(Uw, 4096, WT4a, 2304, 1024);
  wtrans<<<dim3(128, 8),  dim3(32, 8), 0, stream>>>(Sw, 4096, WT4a, 2304, 2048);
  wtrans<<<dim3(32, 32),  dim3(32, 8), 0, stream>>>(Vw, 1024, WTVa, 1024, 0);

  gemm8<<<dim3(20, 32), 512, 0, stream>>>(Afull, WT4a, WTVa, sums);

  epilogue<<<8192, 256, 0, stream>>>(sums, ctm, Wb, Ub, Sb, Vb, outC, outH);
}

// Round 4
// 295.068 us; speedup vs baseline: 1.1586x; 1.0016x over previous
//
#include <hip/hip_runtime.h>

#define B_DIM 8192
#define CELL  1024
#define KA    3328   // A_full row: 1024 x | 1024 htm | 256 spk | 1024 ztm
#define BM    256
#define BN    256
#define BK    64

typedef unsigned short u16;
typedef __attribute__((ext_vector_type(8))) short bf16x8;
typedef __attribute__((ext_vector_type(4))) float f32x4;
typedef __attribute__((ext_vector_type(4))) float fx4;
typedef __attribute__((ext_vector_type(4))) unsigned short u16x4;

__device__ inline u16 f2bf(float f) {
  unsigned u = __float_as_uint(f);
  return (u16)((u + 0x7FFFu + ((u >> 16) & 1u)) >> 16);
}
__device__ inline float sigmoidf(float v) { return 1.0f / (1.0f + __expf(-v)); }

// ---------- prep: fp32 -> bf16 concat into A_full ----------
__global__ void cvt_cat(const float* __restrict__ src, u16* __restrict__ dst,
                        int shift, int colOff, int n4) {
  int i = blockIdx.x * 256 + threadIdx.x;
  if (i >= n4) return;
  int e = i << 2;
  int row = e >> shift;
  int col = e & ((1 << shift) - 1);
  float4 v = *reinterpret_cast<const float4*>(src + e);
  u16x4 o;
  o[0] = f2bf(v.x); o[1] = f2bf(v.y); o[2] = f2bf(v.z); o[3] = f2bf(v.w);
  *reinterpret_cast<u16x4*>(dst + (size_t)row * KA + colOff + col) = o;
}

// ---------- prep: transpose weights [K][N] fp32 -> [Npacked][KT] bf16 ----------
// packed=1: p = (c>>4)*64 + gate*16 + (c&15), where src col j = gate*1024 + c
__global__ void wtrans(const float* __restrict__ src, int N,
                       u16* __restrict__ dst, int KT, int koff, int packed) {
  __shared__ float tile[32][33];
  int n0 = blockIdx.x * 32, k0 = blockIdx.y * 32;
  int tx = threadIdx.x, ty = threadIdx.y;  // 32x8
#pragma unroll
  for (int j = 0; j < 4; ++j)
    tile[ty + j * 8][tx] = src[(size_t)(k0 + ty + j * 8) * N + n0 + tx];
  __syncthreads();
#pragma unroll
  for (int j = 0; j < 4; ++j) {
    int jj = n0 + ty + j * 8;
    int p = packed ? (((jj & 1023) >> 4) << 6) + ((jj >> 10) << 4) + (jj & 15) : jj;
    dst[(size_t)p * KT + koff + k0 + tx] = f2bf(tile[tx][ty + j * 8]);
  }
}

// ---------- fused GEMM + LSTM ----------
__device__ __forceinline__ void gload_lds16(const void* g, void* l) {
  __builtin_amdgcn_global_load_lds((const __attribute__((address_space(1))) void*)g,
                                   (__attribute__((address_space(3))) void*)l,
                                   16, 0, 0);
}

// stage one half (128 rows x 64 k): LDS dest linear, global source slot
// pre-XOR-swizzled (rule 21) so ds_read-with-XOR sees correct data.
__device__ __forceinline__ void stage_half(const u16* __restrict__ g0, int ldk,
                                           u16* ldsTile, int half, int kt,
                                           int wave, int lane) {
#pragma unroll
  for (int k2 = 0; k2 < 2; ++k2) {
    const int r0 = half * 128 + k2 * 64 + wave * 8;
    const int r = r0 + (lane >> 3);
    const int slot = (lane & 7) ^ (lane >> 3);
    const u16* g = g0 + (size_t)r * ldk + kt * 64 + slot * 8;
    gload_lds16((const void*)g, (void*)(ldsTile + r0 * 64));
  }
}

#define LD_A(ASP, QP)                                                              \
  aq[0][0] = *reinterpret_cast<const bf16x8*>((ASP) + aBase0 + (2 * (QP)) * 1024);     \
  aq[0][1] = *reinterpret_cast<const bf16x8*>((ASP) + aBase1 + (2 * (QP)) * 1024);     \
  aq[1][0] = *reinterpret_cast<const bf16x8*>((ASP) + aBase0 + (2 * (QP) + 1) * 1024); \
  aq[1][1] = *reinterpret_cast<const bf16x8*>((ASP) + aBase1 + (2 * (QP) + 1) * 1024);

#define LD_B(BSP)                                                                  \
  _Pragma("unroll")                                                                \
  for (int n = 0; n < 4; ++n) {                                                    \
    br[n][0] = *reinterpret_cast<const bf16x8*>((BSP) + bBase0 + n * 1024);        \
    br[n][1] = *reinterpret_cast<const bf16x8*>((BSP) + bBase1 + n * 1024);        \
  }

#define MFMA_PH(QP)                                                                \
  __builtin_amdgcn_s_setprio(1);                                                   \
  _Pragma("unroll")                                                                \
  for (int q = 0; q < 2; ++q) {                                                    \
    _Pragma("unroll")                                                              \
    for (int n = 0; n < 4; ++n) {                                                  \
      acc[2 * (QP) + q][n] = __builtin_amdgcn_mfma_f32_16x16x32_bf16(              \
          aq[q][0], br[n][0], acc[2 * (QP) + q][n], 0, 0, 0);                      \
      acc[2 * (QP) + q][n] = __builtin_amdgcn_mfma_f32_16x16x32_bf16(              \
          aq[q][1], br[n][1], acc[2 * (QP) + q][n], 0, 0, 0);                      \
    }                                                                              \
  }                                                                                \
  __builtin_amdgcn_s_setprio(0);

#define ENTRY_BAR                                                                  \
  __builtin_amdgcn_sched_barrier(0);                                               \
  __builtin_amdgcn_s_barrier();                                                    \
  asm volatile("s_waitcnt lgkmcnt(0)" ::: "memory");                               \
  __builtin_amdgcn_sched_barrier(0);

#define EXIT_BAR __builtin_amdgcn_s_barrier();

__global__ __launch_bounds__(512, 2) void gemm_fused(
    const u16* __restrict__ Afull, const u16* __restrict__ WT4p,
    const u16* __restrict__ VwT, const float* __restrict__ ctm,
    const float* __restrict__ Wb, const float* __restrict__ Ub,
    const float* __restrict__ Sb, const float* __restrict__ Vb,
    float* __restrict__ outC, float* __restrict__ outH) {
  __shared__ u16 As[2][BM * BK];
  __shared__ u16 Bs[2][BN * BK];
  const int tid = threadIdx.x;
  const int wave = tid >> 6, lane = tid & 63;
  const int wm = wave >> 2, wn = wave & 3;       // 2 x 4 wave grid
  const int lrow = lane & 15, khi = lane >> 4;

  // T1: bijective XCD swizzle (512 % 8 == 0).
  const int bid = blockIdx.x;
  const int tilei = ((bid & 7) << 6) | (bid >> 3);
  const int nb = tilei >> 5, mb = tilei & 31;
  const int m0 = mb * 256;
  const u16* Ag = Afull + (size_t)m0 * KA;            // gates A: cols 0..2303
  const u16* Ah = Afull + (size_t)m0 * KA + 2304;     // hybrid A: ztm cols
  const u16* Bg = WT4p + (size_t)(nb * 256) * 2304;   // packed gate weights

  const int sw = lane & 7;
  const int swz0 = ((0 + khi) ^ sw) * 8;
  const int swz1 = ((4 + khi) ^ sw) * 8;
  const int aBase0 = (wm * 128 + lrow) * 64 + swz0;
  const int aBase1 = (wm * 128 + lrow) * 64 + swz1;
  const int bBase0 = (wn * 64 + lrow) * 64 + swz0;
  const int bBase1 = (wn * 64 + lrow) * 64 + swz1;

  // this lane's output column and its VwT row (hybrid B read direct from global)
  const int co = nb * 64 + wn * 16 + lrow;
  const u16* HgRow = VwT + (size_t)co * 1024;

  f32x4 acc[8][4];
#pragma unroll
  for (int m2 = 0; m2 < 8; ++m2)
#pragma unroll
    for (int n2 = 0; n2 < 4; ++n2) acc[m2][n2] = (f32x4){0.f, 0.f, 0.f, 0.f};
  bf16x8 aq[2][2], br[4][2];
  u16* As0 = As[0]; u16* As1 = As[1]; u16* Bs0 = Bs[0]; u16* Bs1 = Bs[1];

  // ======== gate GEMM: K=2304, 36 k-tiles, verified 8-phase loop ========
  stage_half(Ag, KA, As0, 0, 0, wave, lane);
  stage_half(Ag, KA, As0, 1, 0, wave, lane);
  stage_half(Bg, 2304, Bs0, 0, 0, wave, lane);
  stage_half(Bg, 2304, Bs0, 1, 0, wave, lane);
  stage_half(Bg, 2304, Bs1, 0, 1, wave, lane);
  stage_half(Bg, 2304, Bs1, 1, 1, wave, lane);
  asm volatile("s_waitcnt vmcnt(4)" ::: "memory");
  __builtin_amdgcn_s_barrier();

#pragma unroll 1
  for (int it = 0; it < 18; ++it) {
    const int t = it * 2;
    const bool nl = (t + 2 < 36);
    LD_B(Bs0)
    LD_A(As0, 0)
    stage_half(Ag, KA, As1, 0, t + 1, wave, lane);
    ENTRY_BAR MFMA_PH(0) EXIT_BAR

    LD_A(As0, 1)
    stage_half(Ag, KA, As1, 1, t + 1, wave, lane);
    ENTRY_BAR MFMA_PH(1) EXIT_BAR

    LD_A(As0, 2)
    if (nl) stage_half(Bg, 2304, Bs0, 0, t + 2, wave, lane);
    ENTRY_BAR MFMA_PH(2) EXIT_BAR

    LD_A(As0, 3)
    if (nl) stage_half(Bg, 2304, Bs0, 1, t + 2, wave, lane);
    ENTRY_BAR MFMA_PH(3)
    if (nl) { asm volatile("s_waitcnt vmcnt(4)" ::: "memory"); }
    else    { asm volatile("s_waitcnt vmcnt(0)" ::: "memory"); }
    EXIT_BAR

    LD_B(Bs1)
    LD_A(As1, 0)
    if (nl) stage_half(Ag, KA, As0, 0, t + 2, wave, lane);
    ENTRY_BAR MFMA_PH(0) EXIT_BAR

    LD_A(As1, 1)
    if (nl) stage_half(Ag, KA, As0, 1, t + 2, wave, lane);
    ENTRY_BAR MFMA_PH(1) EXIT_BAR

    LD_A(As1, 2)
    if (nl) stage_half(Bg, 2304, Bs1, 0, t + 3, wave, lane);
    ENTRY_BAR MFMA_PH(2) EXIT_BAR

    LD_A(As1, 3)
    if (nl) stage_half(Bg, 2304, Bs1, 1, t + 3, wave, lane);
    ENTRY_BAR MFMA_PH(3)
    if (nl) { asm volatile("s_waitcnt vmcnt(4)" ::: "memory"); }
    else    { asm volatile("s_waitcnt vmcnt(0)" ::: "memory"); }
    EXIT_BAR
  }

  // ======== hybrid GEMM: ztm @ Vw (K=1024), bulletproof single-buffer ========
  // A staged via verified stage_half/LD_A; B read per-lane direct from global
  // (lane owns VwT row co; VwT is 2MB -> L2-resident).
  f32x4 acch[8];
#pragma unroll
  for (int m2 = 0; m2 < 8; ++m2) acch[m2] = (f32x4){0.f, 0.f, 0.f, 0.f};

#pragma unroll 1
  for (int kt = 0; kt < 16; ++kt) {
    __syncthreads();  // all waves' previous As0 reads retired
    stage_half(Ah, KA, As0, 0, kt, wave, lane);
    stage_half(Ah, KA, As0, 1, kt, wave, lane);
    __syncthreads();  // drains vmcnt(0): staged tile visible to all
    bf16x8 bh0 = *reinterpret_cast<const bf16x8*>(HgRow + kt * 64 + khi * 8);
    bf16x8 bh1 = *reinterpret_cast<const bf16x8*>(HgRow + kt * 64 + 32 + khi * 8);
#pragma unroll
    for (int qp = 0; qp < 4; ++qp) {
      LD_A(As0, qp)
      acch[2 * qp]     = __builtin_amdgcn_mfma_f32_16x16x32_bf16(aq[0][0], bh0, acch[2 * qp], 0, 0, 0);
      acch[2 * qp]     = __builtin_amdgcn_mfma_f32_16x16x32_bf16(aq[0][1], bh1, acch[2 * qp], 0, 0, 0);
      acch[2 * qp + 1] = __builtin_amdgcn_mfma_f32_16x16x32_bf16(aq[1][0], bh0, acch[2 * qp + 1], 0, 0, 0);
      acch[2 * qp + 1] = __builtin_amdgcn_mfma_f32_16x16x32_bf16(aq[1][1], bh1, acch[2 * qp + 1], 0, 0, 0);
    }
  }

  // ======== fused LSTM epilogue (per-wave, fp32, direct to d_out) ========
  const float bf = Wb[co] + Ub[co] + Sb[co];
  const float bi = Wb[1024 + co] + Ub[1024 + co] + Sb[1024 + co];
  const float bo = Wb[2048 + co] + Ub[2048 + co] + Sb[2048 + co];
  const float bc = Wb[3072 + co] + Ub[3072 + co] + Sb[3072 + co];
  const float bv = Vb[co];
#pragma unroll
  for (int mf = 0; mf < 8; ++mf) {
    const int r0 = m0 + wm * 128 + mf * 16 + khi * 4;
#pragma unroll
    for (int j = 0; j < 4; ++j) {
      const size_t idx = (size_t)(r0 + j) * CELL + co;
      float f_ = sigmoidf(acc[mf][0][j] + bf);
      float i_ = sigmoidf(acc[mf][1][j] + bi);
      float o_ = sigmoidf(acc[mf][2][j] + bo);
      float g_ = tanhf(acc[mf][3][j] + bc);
      float fh = sigmoidf(acch[mf][j] + bv);
      float ct = ctm[idx];
      float cc = (f_ + fh) * ct + i_ * g_;
      outC[idx] = cc;
      outH[idx] = tanhf(cc) * o_;
    }
  }
}

extern "C" void kernel_launch(void* const* d_in, const int* in_sizes, int n_in,
                              void* d_out, int out_size, void* d_ws, size_t ws_size,
                              hipStream_t stream) {
  const float* x   = (const float*)d_in[0];
  const float* ctm = (const float*)d_in[1];
  const float* htm = (const float*)d_in[2];
  const float* ztm = (const float*)d_in[3];
  const float* spk = (const float*)d_in[4];
  const float* Ww  = (const float*)d_in[5];
  const float* Wb  = (const float*)d_in[6];
  const float* Uw  = (const float*)d_in[7];
  const float* Ub  = (const float*)d_in[8];
  const float* Vw  = (const float*)d_in[9];
  const float* Vb  = (const float*)d_in[10];
  const float* Sw  = (const float*)d_in[11];
  const float* Sb  = (const float*)d_in[12];

  // workspace (bf16): A_full | WT4 packed | VwT   (~76 MB)
  u16* Afull = (u16*)d_ws;
  u16* WT4p  = Afull + (size_t)B_DIM * KA;
  u16* VwT   = WT4p + (size_t)4096 * 2304;
  float* outC = (float*)d_out;
  float* outH = outC + (size_t)B_DIM * CELL;

  cvt_cat<<<8192, 256, 0, stream>>>(x,   Afull, 10, 0,    2097152);
  cvt_cat<<<8192, 256, 0, stream>>>(htm, Afull, 10, 1024, 2097152);
  cvt_cat<<<2048, 256, 0, stream>>>(spk, Afull, 8,  2048, 524288);
  cvt_cat<<<8192, 256, 0, stream>>>(ztm, Afull, 10, 2304, 2097152);

  wtrans<<<dim3(128, 32), dim3(32, 8), 0, stream>>>(Ww, 4096, WT4p, 2304, 0,    1);
  wtrans<<<dim3(128, 32), dim3(32, 8), 0, stream>>>(Uw, 4096, WT4p, 2304, 1024, 1);
  wtrans<<<dim3(128, 8),  dim3(32, 8), 0, stream>>>(Sw, 4096, WT4p, 2304, 2048, 1);
  wtrans<<<dim3(32, 32),  dim3(32, 8), 0, stream>>>(Vw, 1024, VwT,  1024, 0,    0);

  gemm_fused<<<512, 512, 0, stream>>>(Afull, WT4p, VwT, ctm, Wb, Ub, Sb, Vb, outC, outH);
}